// Round 2
// baseline (211.411 us; speedup 1.0000x reference)
//
#include <hip/hip_runtime.h>

#define D 32
#define EPS 1e-5f
#define TPB 256
#define NB 256          // blocks for the counting-sort passes (fixed chunking)
#define NB2 1024        // blocks for the msg-stats pass

// ======================================================================
// NEW PATH: atomic-light pipeline with dst-order msg permutation
//   memset(small) -> k1_hist -> k2_scan -> k3_scatter -> k4_compute
//                 -> k4b_stats -> k5_reduce
// ======================================================================

// ---- K1: relation histogram (LDS-aggregated) + per-dst counts ----------
__global__ void k1_hist(const int* __restrict__ etype, const int* __restrict__ dst,
                        int E, int R,
                        int* __restrict__ relHist, int* __restrict__ cnt)
{
    __shared__ int lh[1024];
    for (int i = threadIdx.x; i < R; i += TPB) lh[i] = 0;
    __syncthreads();
    for (int e = blockIdx.x * TPB + threadIdx.x; e < E; e += gridDim.x * TPB) {
        atomicAdd(&lh[etype[e]], 1);
        atomicAdd(&cnt[dst[e]], 1);
    }
    __syncthreads();
    for (int r = threadIdx.x; r < R; r += TPB)
        if (lh[r]) atomicAdd(&relHist[r], lh[r]);
}

// ---- K2: rel scan + task list + dst exclusive scan (single block) ------
__global__ __launch_bounds__(1024)
void k2_scan(const int* __restrict__ relHist, int R, int E, int N,
             int* __restrict__ rel_start, int* __restrict__ cursor_rel,
             int* __restrict__ task_rel, int* __restrict__ task_start,
             int* __restrict__ n_tasks,
             const int* __restrict__ cnt,
             int* __restrict__ dst_base, int* __restrict__ cursor_dst)
{
    const int t = threadIdx.x;
    __shared__ int sb[1024];
    __shared__ int s_start[1025];
    __shared__ int s_tbase[1024];

    // relation exclusive scan + task bases (R tiny, serial on t0)
    if (t == 0) {
        int acc = 0, tb = 0;
        for (int r = 0; r < R; ++r) {
            s_start[r] = acc; s_tbase[r] = tb;
            const int v = relHist[r];
            acc += v;
            tb  += (v + TPB - 1) / TPB;
        }
        s_start[R] = acc;
        *n_tasks = tb;
    }
    __syncthreads();
    if (t < R) {
        const int st = s_start[t];
        rel_start[t]  = st;
        cursor_rel[t] = st;
        const int tot = s_start[t + 1] - st;
        const int nb  = (tot + TPB - 1) / TPB;
        const int tb  = s_tbase[t];
        for (int b = 0; b < nb; ++b) {
            task_rel[tb + b]   = t;
            task_start[tb + b] = st + b * TPB;
        }
    }
    if (t == 0) rel_start[R] = s_start[R];

    // dst exclusive scan over N bins (chunk per thread + block scan)
    const int chunk = (N + 1023) >> 10;
    const int lo = t * chunk, hi = min(N, lo + chunk);
    int part = 0;
    for (int i = lo; i < hi; ++i) part += cnt[i];
    sb[t] = part;
    __syncthreads();
    for (int off = 1; off < 1024; off <<= 1) {
        const int v = (t >= off) ? sb[t - off] : 0;
        __syncthreads();
        sb[t] += v;
        __syncthreads();
    }
    int base = sb[t] - part;            // exclusive prefix for this chunk
    for (int i = lo; i < hi; ++i) {
        dst_base[i]   = base;
        cursor_dst[i] = base;
        base += cnt[i];
    }
    if (t == 0) dst_base[N] = E;
}

// ---- K3: scatter into rel-sorted order + assign dst-order slot ---------
__global__ void k3_scatter(const int* __restrict__ src, const int* __restrict__ dst,
                           const int* __restrict__ etype, int E, int R, int chunk,
                           int* __restrict__ cursor_rel, int* __restrict__ cursor_dst,
                           int* __restrict__ ssrc, int* __restrict__ tpos)
{
    __shared__ int lh[1024];
    __shared__ int lcur[1024];
    for (int r = threadIdx.x; r < R; r += TPB) lh[r] = 0;
    __syncthreads();
    const int lo = blockIdx.x * chunk, hi = min(E, lo + chunk);
    for (int e = lo + threadIdx.x; e < hi; e += TPB)
        atomicAdd(&lh[etype[e]], 1);
    __syncthreads();
    for (int r = threadIdx.x; r < R; r += TPB)
        lcur[r] = lh[r] ? atomicAdd(&cursor_rel[r], lh[r]) : 0;
    __syncthreads();
    for (int e = lo + threadIdx.x; e < hi; e += TPB) {
        const int p = atomicAdd(&lcur[etype[e]], 1);   // LDS atomic
        ssrc[p] = src[e];
        tpos[p] = atomicAdd(&cursor_dst[dst[e]], 1);   // dst-order slot
    }
}

// ---- K4: per-task gather + matmul + relu; plain stores to msg[tpos] ----
// (stats removed — they are computed per-dim in k4b_stats; the R1 bug was
//  summing ps/pq ACROSS dims here, which poisoned the BN statistics)
__global__ __launch_bounds__(TPB)
void k4_compute(const float* __restrict__ h, const float* __restrict__ W,
                const int* __restrict__ rel_start,
                const int* __restrict__ task_rel, const int* __restrict__ task_start,
                const int* __restrict__ n_tasks_p,
                const int* __restrict__ ssrc, const int* __restrict__ tpos,
                float* __restrict__ msg)
{
    const int task = blockIdx.x;
    if (task >= *n_tasks_p) return;
    const int r      = task_rel[task];
    const int start  = task_start[task];
    const int relEnd = rel_start[r + 1];
    const int e      = start + threadIdx.x;
    if (e >= relEnd) return;

    const float* Wr = W + (size_t)__builtin_amdgcn_readfirstlane(r) * (D * D);

    const int s  = ssrc[e];
    const int tp = tpos[e];
    float acc[D];
#pragma unroll
    for (int o = 0; o < D; ++o) acc[o] = 0.f;
    const float4* hp = (const float4*)(h + (size_t)s * D);
#pragma unroll 4
    for (int c = 0; c < D / 4; ++c) {
        const float4 hv = hp[c];
#pragma unroll
        for (int j = 0; j < 4; ++j) {
            const float hd = (j == 0) ? hv.x : (j == 1) ? hv.y : (j == 2) ? hv.z : hv.w;
            const int d = c * 4 + j;
#pragma unroll
            for (int o = 0; o < D; ++o)
                acc[o] = fmaf(hd, Wr[d * D + o], acc[o]);
        }
    }
    float4* mp = (float4*)(msg + (size_t)tp * D);
#pragma unroll
    for (int c = 0; c < D / 4; ++c) {
        float4 v;
        v.x = fmaxf(acc[4 * c],     0.f);
        v.y = fmaxf(acc[4 * c + 1], 0.f);
        v.z = fmaxf(acc[4 * c + 2], 0.f);
        v.w = fmaxf(acc[4 * c + 3], 0.f);
        mp[c] = v;
    }
}

// ---- K4b: per-dim BN stats from msg (coalesced linear read) ------------
// thread's dim o = tid&31 is FIXED -> per-dim partials (correct indexing)
__global__ __launch_bounds__(TPB)
void k4b_stats(const float* __restrict__ msg, int E,
               float* __restrict__ stat_sum, float* __restrict__ stat_sq)
{
    __shared__ float s_aux[2 * TPB];
    const int tid = threadIdx.x;
    const int o   = tid & (D - 1);
    const int rpb = TPB / D;                 // 8 rows per block-step
    float ps = 0.f, pq = 0.f;
    for (int p = blockIdx.x * rpb + (tid >> 5); p < E; p += gridDim.x * rpb) {
        const float v = msg[(size_t)p * D + o];
        ps += v; pq += v * v;
    }
    s_aux[tid]       = ps;
    s_aux[TPB + tid] = pq;
    __syncthreads();
    if (tid < D) {
        float ss = 0.f, sq = 0.f;
#pragma unroll
        for (int c = 0; c < TPB / D; ++c) {
            ss += s_aux[c * D + tid];
            sq += s_aux[TPB + c * D + tid];
        }
        atomicAdd(&stat_sum[tid], ss);
        atomicAdd(&stat_sq[tid], sq);
    }
}

// ---- K5: segment-sum over contiguous dst segments + BN affine + mean ---
__global__ __launch_bounds__(TPB)
void k5_reduce(const float* __restrict__ msg,
               const int* __restrict__ dst_base,
               const float* __restrict__ stat_sum, const float* __restrict__ stat_sq,
               const float* __restrict__ gamma, const float* __restrict__ beta,
               float invE, int N, float* __restrict__ out)
{
    __shared__ float s_sc[D], s_sh[D];
    const int tid = threadIdx.x;
    if (tid < D) {
        const float mu  = stat_sum[tid] * invE;
        const float var = fmaxf(stat_sq[tid] * invE - mu * mu, 0.f);
        const float is  = rsqrtf(var + EPS);
        const float sc  = gamma[tid] * is;
        s_sc[tid] = sc;
        s_sh[tid] = fmaf(-mu, sc, beta[tid]);
    }
    __syncthreads();
    const int o    = tid & (D - 1);
    const int node = blockIdx.x * (TPB / D) + (tid >> 5);
    if (node >= N) return;
    const int b0 = dst_base[node], b1 = dst_base[node + 1];
    float v = 0.f;
    for (int p = b0; p < b1; ++p) v += msg[(size_t)p * D + o];
    const float c = (float)(b1 - b0);
    out[(size_t)node * D + o] = fmaf(v, s_sc[o], s_sh[o] * c) / fmaxf(c, 1.0f);
}

// ======================================================================
// OLD PATH (fallback when workspace is too small) — unchanged, verified
// ======================================================================

__global__ void hist2_kernel(const int* __restrict__ etype, int E, int R, int chunk,
                             int* __restrict__ blockHistT)   // [R][NB]
{
    __shared__ int lh[1024];
    for (int i = threadIdx.x; i < R; i += TPB) lh[i] = 0;
    __syncthreads();
    const int lo = blockIdx.x * chunk, hi = min(E, lo + chunk);
    for (int e = lo + threadIdx.x; e < hi; e += TPB)
        atomicAdd(&lh[etype[e]], 1);
    __syncthreads();
    for (int r = threadIdx.x; r < R; r += TPB)
        blockHistT[r * NB + blockIdx.x] = lh[r];
}

__global__ void scan2_kernel(int* __restrict__ blockHistT, int R,
                             int* __restrict__ rel_start,
                             int* __restrict__ task_rel, int* __restrict__ task_start,
                             int* __restrict__ n_tasks)
{
    __shared__ int tot[1024];
    __shared__ int s_start[1025];
    __shared__ int s_tbase[1024];
    const int r = threadIdx.x;
    if (r < R) {
        int acc = 0;
        int* p = blockHistT + r * NB;
        for (int b = 0; b < NB; ++b) { int v = p[b]; p[b] = acc; acc += v; }
        tot[r] = acc;
    }
    __syncthreads();
    if (threadIdx.x == 0) {
        int acc = 0, tb = 0;
        for (int rr = 0; rr < R; ++rr) {
            s_start[rr] = acc; s_tbase[rr] = tb;
            acc += tot[rr];
            tb  += (tot[rr] + TPB - 1) / TPB;
        }
        s_start[R] = acc;
        rel_start[R] = acc;
        *n_tasks = tb;
    }
    __syncthreads();
    if (r < R) {
        const int st = s_start[r];
        rel_start[r] = st;
        const int nb = (tot[r] + TPB - 1) / TPB;
        const int tb = s_tbase[r];
        for (int b = 0; b < nb; ++b) {
            task_rel[tb + b]   = r;
            task_start[tb + b] = st + b * TPB;
        }
    }
}

__global__ void scatter2_kernel(const int* __restrict__ src, const int* __restrict__ dst,
                                const int* __restrict__ etype, int E, int R, int chunk,
                                const int* __restrict__ blockHistT,
                                const int* __restrict__ rel_start,
                                int* __restrict__ ssrc, int* __restrict__ sdst)
{
    __shared__ int cur[1024];
    for (int r = threadIdx.x; r < R; r += TPB)
        cur[r] = rel_start[r] + blockHistT[r * NB + blockIdx.x];
    __syncthreads();
    const int lo = blockIdx.x * chunk, hi = min(E, lo + chunk);
    for (int e = lo + threadIdx.x; e < hi; e += TPB) {
        const int p = atomicAdd(&cur[etype[e]], 1);   // LDS atomic only
        ssrc[p] = src[e];
        sdst[p] = dst[e];
    }
}

__global__ __launch_bounds__(TPB)
void rgcn_main(const float* __restrict__ h, const float* __restrict__ W,
               const int* __restrict__ rel_start,
               const int* __restrict__ task_rel, const int* __restrict__ task_start,
               const int* __restrict__ n_tasks_p,
               const int* __restrict__ ssrc, const int* __restrict__ sdst,
               float* __restrict__ out,
               float* __restrict__ stat_sum, float* __restrict__ stat_sq,
               float* __restrict__ cnt)
{
    __shared__ float s_tile[TPB * 33];
    __shared__ int   s_src[TPB];
    __shared__ int   s_dst[TPB];
    __shared__ float s_aux[2 * TPB];

    const int task = blockIdx.x;
    if (task >= *n_tasks_p) return;
    const int r      = task_rel[task];
    const int start  = task_start[task];
    const int relEnd = rel_start[r + 1];
    const int nE     = min(TPB, relEnd - start);
    const int tid    = threadIdx.x;

    if (tid < nE) {
        s_src[tid] = ssrc[start + tid];
        s_dst[tid] = sdst[start + tid];
    }
    __syncthreads();

    for (int i = tid; i < nE * 8; i += TPB) {
        const int row = i >> 3, seg = i & 7;
        const float4 v = *(const float4*)(h + (size_t)s_src[row] * D + seg * 4);
        float* p = &s_tile[row * 33 + seg * 4];
        p[0] = v.x; p[1] = v.y; p[2] = v.z; p[3] = v.w;
    }
    __syncthreads();

    const float* Wr = W + (size_t)__builtin_amdgcn_readfirstlane(r) * (D * D);

    float acc[D];
#pragma unroll
    for (int o = 0; o < D; ++o) acc[o] = 0.f;

    if (tid < nE) {
#pragma unroll 4
        for (int d = 0; d < D; ++d) {
            const float hd = s_tile[tid * 33 + d];
#pragma unroll
            for (int o = 0; o < D; ++o)
                acc[o] = fmaf(hd, Wr[d * D + o], acc[o]);
        }
#pragma unroll
        for (int o = 0; o < D; ++o) acc[o] = fmaxf(acc[o], 0.f);
        atomicAdd(&cnt[s_dst[tid]], 1.0f);
    }
    __syncthreads();

    if (tid < nE) {
#pragma unroll
        for (int o = 0; o < D; ++o) s_tile[tid * 33 + o] = acc[o];
    }
    __syncthreads();

    float ps = 0.f, pq = 0.f;
    for (int i = tid; i < nE * D; i += TPB) {
        const int row = i >> 5, o = i & 31;
        const float v = s_tile[row * 33 + o];
        atomicAdd(&out[(size_t)s_dst[row] * D + o], v);
        ps += v; pq += v * v;
    }
    s_aux[tid]       = ps;
    s_aux[TPB + tid] = pq;
    __syncthreads();
    if (tid < D) {
        float ss = 0.f, sq = 0.f;
#pragma unroll
        for (int c = 0; c < TPB / D; ++c) {
            ss += s_aux[c * D + tid];
            sq += s_aux[TPB + c * D + tid];
        }
        atomicAdd(&stat_sum[tid], ss);
        atomicAdd(&stat_sq[tid], sq);
    }
}

__global__ void finalize_kernel(float* __restrict__ out, const float* __restrict__ cnt,
                                const float* __restrict__ stat_sum,
                                const float* __restrict__ stat_sq,
                                const float* __restrict__ gamma,
                                const float* __restrict__ beta,
                                float invE, int total)
{
    const int i = blockIdx.x * TPB + threadIdx.x;
    if (i >= total) return;
    const int o    = i & 31;
    const int node = i >> 5;
    const float mu  = stat_sum[o] * invE;
    const float var = fmaxf(stat_sq[o] * invE - mu * mu, 0.f);
    const float is  = rsqrtf(var + EPS);
    const float sc  = gamma[o] * is;
    const float sh  = fmaf(-mu, sc, beta[o]);
    const float c   = cnt[node];
    out[i] = fmaf(out[i], sc, sh * c) / fmaxf(c, 1.0f);
}

// ======================================================================
extern "C" void kernel_launch(void* const* d_in, const int* in_sizes, int n_in,
                              void* d_out, int out_size, void* d_ws, size_t ws_size,
                              hipStream_t stream)
{
    const float* h     = (const float*)d_in[0];
    const float* W     = (const float*)d_in[1];
    const float* gamma = (const float*)d_in[2];
    const float* beta  = (const float*)d_in[3];
    const int*   src   = (const int*)d_in[4];
    const int*   dst   = (const int*)d_in[5];
    const int*   etype = (const int*)d_in[6];
    float* out = (float*)d_out;

    const int E = in_sizes[4];
    const int N = in_sizes[0] / D;
    const int R = in_sizes[1] / (D * D);
    const int T = R + (E + TPB - 1) / TPB;        // max task count
    const int chunk = (E + NB - 1) / NB;

    // ---------------- new-path workspace layout (dword offsets) ----------
    const size_t o_stat_sum   = 0;
    const size_t o_stat_sq    = o_stat_sum + D;
    const size_t o_relHist    = o_stat_sq + D;
    const size_t o_cursor_rel = o_relHist + R;
    const size_t o_n_tasks    = o_cursor_rel + R;
    const size_t o_cnt        = o_n_tasks + 1;
    const size_t zwords       = o_cnt + (size_t)N;          // zeroed prefix
    const size_t o_rel_start  = zwords;
    const size_t o_task_rel   = o_rel_start + R + 1;
    const size_t o_task_start = o_task_rel + T;
    const size_t o_dst_base   = o_task_start + T;
    const size_t o_cursor_dst = o_dst_base + N + 1;
    const size_t o_ssrc       = o_cursor_dst + N;
    const size_t o_tpos       = o_ssrc + (size_t)E;
    const size_t o_msg        = (o_tpos + (size_t)E + 3) & ~(size_t)3;  // 16B align
    const size_t total_words  = o_msg + (size_t)E * D;

    if (ws_size >= total_words * 4) {
        // ------------------------- NEW PATH ------------------------------
        float* stat_sum   = (float*)d_ws + o_stat_sum;
        float* stat_sq    = (float*)d_ws + o_stat_sq;
        int*   relHist    = (int*)d_ws + o_relHist;
        int*   cursor_rel = (int*)d_ws + o_cursor_rel;
        int*   n_tasks    = (int*)d_ws + o_n_tasks;
        int*   cnt        = (int*)d_ws + o_cnt;
        int*   rel_start  = (int*)d_ws + o_rel_start;
        int*   task_rel   = (int*)d_ws + o_task_rel;
        int*   task_start = (int*)d_ws + o_task_start;
        int*   dst_base   = (int*)d_ws + o_dst_base;
        int*   cursor_dst = (int*)d_ws + o_cursor_dst;
        int*   ssrc       = (int*)d_ws + o_ssrc;
        int*   tpos       = (int*)d_ws + o_tpos;
        float* msg        = (float*)d_ws + o_msg;

        hipMemsetAsync(d_ws, 0, zwords * 4, stream);

        k1_hist<<<NB, TPB, 0, stream>>>(etype, dst, E, R, relHist, cnt);
        k2_scan<<<1, 1024, 0, stream>>>(relHist, R, E, N,
                                        rel_start, cursor_rel,
                                        task_rel, task_start, n_tasks,
                                        cnt, dst_base, cursor_dst);
        k3_scatter<<<NB, TPB, 0, stream>>>(src, dst, etype, E, R, chunk,
                                           cursor_rel, cursor_dst, ssrc, tpos);
        k4_compute<<<T, TPB, 0, stream>>>(h, W, rel_start, task_rel, task_start,
                                          n_tasks, ssrc, tpos, msg);
        k4b_stats<<<NB2, TPB, 0, stream>>>(msg, E, stat_sum, stat_sq);
        k5_reduce<<<(N + TPB / D - 1) / (TPB / D), TPB, 0, stream>>>(
            msg, dst_base, stat_sum, stat_sq, gamma, beta,
            1.0f / (float)E, N, out);
        return;
    }

    // --------------------------- OLD PATH --------------------------------
    float* stat_sum  = (float*)d_ws;
    float* stat_sq   = stat_sum + D;
    float* cnt       = stat_sq + D;
    int*   rel_start = (int*)(cnt + N);
    int*   n_tasks   = rel_start + R + 1;
    int*   task_rel  = n_tasks + 1;
    int*   task_start= task_rel + T;
    int*   blockHistT= task_start + T;
    int*   ssrc      = blockHistT + R * NB;
    int*   sdst      = ssrc + E;

    hipMemsetAsync(d_ws, 0, sizeof(float) * (size_t)(2 * D + N), stream);
    hipMemsetAsync(d_out, 0, sizeof(float) * (size_t)out_size, stream);

    hist2_kernel<<<NB, TPB, 0, stream>>>(etype, E, R, chunk, blockHistT);
    scan2_kernel<<<1, TPB, 0, stream>>>(blockHistT, R, rel_start,
                                        task_rel, task_start, n_tasks);
    scatter2_kernel<<<NB, TPB, 0, stream>>>(src, dst, etype, E, R, chunk,
                                            blockHistT, rel_start, ssrc, sdst);
    rgcn_main<<<T, TPB, 0, stream>>>(h, W, rel_start, task_rel, task_start,
                                     n_tasks, ssrc, sdst, out,
                                     stat_sum, stat_sq, cnt);
    finalize_kernel<<<(N * D + TPB - 1) / TPB, TPB, 0, stream>>>(
        out, cnt, stat_sum, stat_sq, gamma, beta, 1.0f / (float)E, N * D);
}